// Round 6
// baseline (70.409 us; speedup 1.0000x reference)
//
#include <hip/hip_runtime.h>
#include <math.h>

#define BB 4
#define LL 512
#define NROW (BB*LL)      // 2048
#define DD 128
#define DEG 511.0f
#define SCALE 0.08838834764831845f   // 1/sqrt(128)

typedef short bf16x8 __attribute__((ext_vector_type(8)));
typedef float f32x4 __attribute__((ext_vector_type(4)));

static __device__ __forceinline__ ushort f2bf(float f) {
  unsigned u = __float_as_uint(f);
  u = (u + 0x7fffu + ((u >> 16) & 1u)) >> 16;   // RNE
  return (ushort)u;
}

// =============== K1: fused front+adjacency ===============
// grid (8,8,4), 256 thr. Per block: compute embeddings (VALU) + projections
// (MFMA, weights bf16-staged in LDS) for its 64 i-rows and 64 j-rows, then
// the 64x64 adjacency tile + argmin/diff partials. No global intermediates.
__global__ __launch_bounds__(256) void k_fused(
    const float* __restrict__ inputs, const float* __restrict__ coords,
    const float* __restrict__ cc,
    const float* __restrict__ Wc, const float* __restrict__ bc,
    const float* __restrict__ Wcc, const float* __restrict__ bcc,
    const float* __restrict__ Wa, const float* __restrict__ ba,
    const float* __restrict__ Wb, const float* __restrict__ bb,
    float* __restrict__ diffpart, float* __restrict__ minval, int* __restrict__ minidx) {
  __shared__ ushort E1[64][136], E2[64][136];
  __shared__ ushort aT[64][136], acT[64][136], bT[64][136], bcT[64][136];
  __shared__ float bcS[128], bccS[128], biasS[128], headIn[12];
  __shared__ float red[256];
  __shared__ __align__(16) char uni[34816];   // union: fin1/fin2 (6 KB) | WT (34 KB)
  float (*fin1)[12] = (float(*)[12])uni;
  float (*fin2)[12] = (float(*)[12])(uni + 3072);
  ushort (*WT)[136] = (ushort(*)[136])uni;

  int t = threadIdx.x;
  int ix = blockIdx.x, jy = blockIdx.y, b = blockIdx.z;
  int i0 = b*LL + ix*64, j0 = b*LL + jy*64;
  int lane = t & 63, wave = t >> 6;
  int d = t & 127;

  if (t < 128) { bcS[t] = bc[t]; bccS[t] = bcc[t]; }
  if (t < 12)  headIn[t] = (t < 10) ? inputs[(size_t)(b*LL)*10 + t] : 0.f;
  float wcR[12], wccR[12];
#pragma unroll
  for (int k = 0; k < 12; ++k) { wcR[k] = Wc[k*DD + d]; wccR[k] = Wcc[k*DD + d]; }
  __syncthreads();

  for (int side = 0; side < 2; ++side) {
    int rows0 = side ? j0 : i0;
    const float* W    = side ? Wb : Wa;
    const float* bias = side ? bb : ba;
    // S1: features
    for (int idx = t; idx < 768; idx += 256) {
      int r = idx / 12, k = idx - r*12;
      int grow = rows0 + r;
      float f1, f2;
      if (k < 10) { float v = inputs[(size_t)grow*10 + k]; f1 = v; f2 = v - headIn[k]; }
      else        { f1 = coords[(size_t)grow*2 + (k-10)]; f2 = cc[(size_t)grow*2 + (k-10)]; }
      fin1[r][k] = f1; fin2[r][k] = f2;
    }
    __syncthreads();
    // S2: embeddings (each thread: fixed d, 32 rows)
    {
      int r0 = t >> 7;
      for (int it = 0; it < 32; ++it) {
        int r = r0 + it*2;
        float e1 = bcS[d], e2 = bccS[d];
#pragma unroll
        for (int k = 0; k < 12; ++k) { e1 += fin1[r][k]*wcR[k]; e2 += fin2[r][k]*wccR[k]; }
        E1[r][d] = f2bf(e1); E2[r][d] = f2bf(e2);
      }
    }
    __syncthreads();   // fin dead -> WT may overwrite
    // S3: stage transposed bf16 weight + bias
    for (int idx = t; idx < 16384; idx += 256) {
      int kk = idx >> 7, dd = idx & 127;
      WT[dd][kk] = f2bf(W[idx]);
    }
    if (t < 128) biasS[t] = bias[t];
    __syncthreads();
    // S4: projection MFMA: out = E @ W + bias (16 rows per wave)
    {
      ushort (*o1)[136] = side ? bT : aT;
      ushort (*o2)[136] = side ? bcT : acT;
      int rloc = lane & 15, koff = (lane >> 4)*8;
      int rbase = wave*16;
      for (int ct = 0; ct < 8; ++ct) {
        f32x4 p1 = {0.f,0.f,0.f,0.f}, p2 = {0.f,0.f,0.f,0.f};
#pragma unroll
        for (int ks = 0; ks < 4; ++ks) {
          bf16x8 ef1 = *(const bf16x8*)&E1[rbase + rloc][ks*32 + koff];
          bf16x8 ef2 = *(const bf16x8*)&E2[rbase + rloc][ks*32 + koff];
          bf16x8 wf  = *(const bf16x8*)&WT[ct*16 + rloc][ks*32 + koff];
          p1 = __builtin_amdgcn_mfma_f32_16x16x32_bf16(ef1, wf, p1, 0,0,0);
          p2 = __builtin_amdgcn_mfma_f32_16x16x32_bf16(ef2, wf, p2, 0,0,0);
        }
        int col = ct*16 + rloc;
        float bv = biasS[col];
#pragma unroll
        for (int r = 0; r < 4; ++r) {
          int row = rbase + (lane>>4)*4 + r;
          o1[row][col] = f2bf(p1[r] + bv);
          o2[row][col] = f2bf(p2[r] + bv);
        }
      }
    }
    __syncthreads();
  }

  // adjacency: A-frags from aT/acT, B-frags from bT/bcT
  int rloc = lane & 15, koff = (lane >> 4)*8;
  bf16x8 av[4], acv[4];
#pragma unroll
  for (int ks = 0; ks < 4; ++ks) {
    av[ks]  = *(const bf16x8*)&aT[wave*16 + rloc][ks*32 + koff];
    acv[ks] = *(const bf16x8*)&acT[wave*16 + rloc][ks*32 + koff];
  }
  f32x4 zf = {0.f,0.f,0.f,0.f};
  f32x4 acc[4], accc[4];
#pragma unroll
  for (int jt = 0; jt < 4; ++jt) { acc[jt] = zf; accc[jt] = zf; }
#pragma unroll
  for (int ks = 0; ks < 4; ++ks) {
#pragma unroll
    for (int jt = 0; jt < 4; ++jt) {
      bf16x8 bv  = *(const bf16x8*)&bT[jt*16 + rloc][ks*32 + koff];
      bf16x8 bcv = *(const bf16x8*)&bcT[jt*16 + rloc][ks*32 + koff];
      acc[jt]  = __builtin_amdgcn_mfma_f32_16x16x32_bf16(av[ks],  bv,  acc[jt],  0,0,0);
      accc[jt] = __builtin_amdgcn_mfma_f32_16x16x32_bf16(acv[ks], bcv, accc[jt], 0,0,0);
    }
  }
  // epilogue (R2-verbatim): C row=(lane>>4)*4+reg, col=lane&15
  int g = lane >> 4, c = lane & 15;
  float sq = 0.f;
#pragma unroll
  for (int r = 0; r < 4; ++r) {
    float mn = INFINITY; int mi = -1;
#pragma unroll
    for (int jt = 0; jt < 4; ++jt) {
      float v  = acc[jt][r]  * SCALE;
      float vc = accc[jt][r] * SCALE;
      float dd = v - vc;
      sq += dd*dd;
      int j = j0 + jt*16 + c;
      if (v < mn || (v == mn && j > mi)) { mn = v; mi = j; }
    }
#pragma unroll
    for (int msk = 1; msk < 16; msk <<= 1) {
      float ov = __shfl_xor(mn, msk);
      int   oi = __shfl_xor(mi, msk);
      if (ov < mn || (ov == mn && oi > mi)) { mn = ov; mi = oi; }
    }
    if (c == 0) {
      int gi = i0 + wave*16 + g*4 + r;
      minval[gi*8 + jy] = mn;
      minidx[gi*8 + jy] = mi;
    }
  }
  red[t] = sq;
  __syncthreads();
  for (int off = 128; off > 0; off >>= 1) {
    if (t < off) red[t] += red[t+off];
    __syncthreads();
  }
  if (t == 0) diffpart[(b*8 + jy)*8 + ix] = red[0];
}

// =============== K2: per-batch tail (x recompute, P/Q MFMA, sb, h1 stream, final) ========
__global__ __launch_bounds__(1024) void k_tail2(
    const float* __restrict__ inputs, const float* __restrict__ coords,
    const float* __restrict__ cc,
    const float* __restrict__ Wc, const float* __restrict__ bc,
    const float* __restrict__ Wcc, const float* __restrict__ bcc,
    const float* __restrict__ W1l, const float* __restrict__ b1l,
    const float* __restrict__ W1r,
    const float* __restrict__ minval, const int* __restrict__ minidx,
    const float* __restrict__ diffpart, const float* __restrict__ targets,
    const float* __restrict__ W2l, const float* __restrict__ b2l,
    const float* __restrict__ W2r,
    float* __restrict__ Pg, float* __restrict__ Qg, float* __restrict__ out) {
  __shared__ ushort W1lT[128][136], W1rT[128][136];
  __shared__ ushort xT[128][136];
  __shared__ float finC1[128][12], finC2[128][12];
  __shared__ float dbcS[128], headIn[12];
  __shared__ float xs[128], sbv[128];
  __shared__ float part[8][128];
  __shared__ int aminL[LL];
  __shared__ float dred[256];

  int b = blockIdx.x, t = threadIdx.x;
  int d = t & 127, h = t >> 7;      // h: 0..7
  int lane = t & 63;

  // T0: stage transposed bf16 W1l/W1r, dbc, head
  for (int idx = t; idx < 16384; idx += 1024) {
    int kk = idx >> 7, dd = idx & 127;
    W1lT[dd][kk] = f2bf(W1l[idx]);
    W1rT[dd][kk] = f2bf(W1r[idx]);
  }
  if (t < 128) dbcS[t] = bc[t] - bcc[t];
  if (t < 12)  headIn[t] = (t < 10) ? inputs[(size_t)(b*LL)*10 + t] : 0.f;
  float wcR[12], wccR[12];
#pragma unroll
  for (int k = 0; k < 12; ++k) { wcR[k] = Wc[k*DD + d]; wccR[k] = Wcc[k*DD + d]; }

  // T1: chunks of 128 rows: x compute + P,Q projection
  float csx = 0.f;
  for (int cch = 0; cch < 4; ++cch) {
    int rows0 = b*LL + cch*128;
    __syncthreads();   // prev chunk's xT/finC consumers done; T0 done before first use
    for (int idx = t; idx < 1536; idx += 1024) {
      int r = idx / 12, k = idx - r*12;
      int grow = rows0 + r;
      float f1, f2;
      if (k < 10) { float v = inputs[(size_t)grow*10 + k]; f1 = v; f2 = v - headIn[k]; }
      else        { f1 = coords[(size_t)grow*2 + (k-10)]; f2 = cc[(size_t)grow*2 + (k-10)]; }
      finC1[r][k] = f1; finC2[r][k] = f2;
    }
    __syncthreads();
    // x for rows h*16..h*16+15 of this chunk
    for (int rr = 0; rr < 16; ++rr) {
      int r = h*16 + rr;
      float xv = dbcS[d];
#pragma unroll
      for (int k = 0; k < 12; ++k) xv += finC1[r][k]*wcR[k] - finC2[r][k]*wccR[k];
      xT[r][d] = f2bf(xv);
      csx += xv;
    }
    __syncthreads();
    // P,Q via MFMA: 16 waves = 8 rowgroups x 2 matrices
    {
      int w = t >> 6;
      int rg = w & 7, mat = w >> 3;
      int rloc = lane & 15, koff = (lane >> 4)*8;
      const ushort (*WTp)[136] = mat ? W1rT : W1lT;
      float* dst = mat ? Qg : Pg;
      for (int ct = 0; ct < 8; ++ct) {
        f32x4 p = {0.f,0.f,0.f,0.f};
#pragma unroll
        for (int ks = 0; ks < 4; ++ks) {
          bf16x8 af = *(const bf16x8*)&xT[rg*16 + rloc][ks*32 + koff];
          bf16x8 wf = *(const bf16x8*)&WTp[ct*16 + rloc][ks*32 + koff];
          p = __builtin_amdgcn_mfma_f32_16x16x32_bf16(af, wf, p, 0,0,0);
        }
        int col = ct*16 + rloc;
#pragma unroll
        for (int r = 0; r < 4; ++r) {
          int grow = rows0 + rg*16 + (lane>>4)*4 + r;
          dst[(size_t)grow*DD + col] = p[r];
        }
      }
    }
  }
  __syncthreads();

  // T2: colsum combine + T3: argmin finalize
  part[h][d] = csx;
  if (t < LL) {
    int row = b*LL + t;
    float mv = minval[row*8]; int mi = minidx[row*8];
#pragma unroll
    for (int ch = 1; ch < 8; ++ch) {
      float v = minval[row*8 + ch]; int i2 = minidx[row*8 + ch];
      if (v < mv || (v == mv && i2 > mi)) { mv = v; mi = i2; }
    }
    aminL[t] = mi;
  }
  __syncthreads();
  if (h == 0) {
    float v = 0.f;
#pragma unroll
    for (int q = 0; q < 8; ++q) v += part[q][d];
    xs[d] = v;
  }
  __syncthreads();
  // T4: sb = colsum(x) @ W1l (f32 weights from global)
  {
    float acc = 0.f;
#pragma unroll
    for (int k = h*16; k < h*16 + 16; ++k) acc += xs[k] * W1l[k*DD + d];
    part[h][d] = acc;
  }
  __syncthreads();
  if (h == 0) {
    float v = 0.f;
#pragma unroll
    for (int q = 0; q < 8; ++q) v += part[q][d];
    sbv[d] = v;
  }
  __syncthreads();
  float base = sbv[d] * (1.0f/DEG) + b1l[d];
  // T6: stream h1, accumulate colsum(h1)
  float csum = 0.f;
  int l0 = h*64;
#pragma unroll 4
  for (int r = 0; r < 64; ++r) {
    int li = l0 + r;
    int am = aminL[li];
    float v = base - Pg[(size_t)am*DD + d] * (1.0f/DEG) + Qg[(size_t)(b*LL + li)*DD + d];
    csum += fmaxf(v, 0.f);
  }
  part[h][d] = csum;
  __syncthreads();
  if (h == 0) {
    float colsum = 0.f;
#pragma unroll
    for (int q = 0; q < 8; ++q) colsum += part[q][d];
    int amh = aminL[0];
    int am2 = aminL[amh - b*LL];
    float h1head = fmaxf(base - Pg[(size_t)amh*DD + d]*(1.0f/DEG) + Qg[(size_t)(b*LL)*DD + d], 0.f);
    float h1am   = fmaxf(base - Pg[(size_t)am2*DD + d]*(1.0f/DEG) + Qg[(size_t)amh*DD + d], 0.f);
    float agg = (colsum - h1am) * (1.0f/DEG);
    part[0][d] = agg * W2l[d] + h1head * W2r[d];
  }
  __syncthreads();
  if (t < 64) {
    float v = part[0][t] + part[0][t + 64];
#pragma unroll
    for (int msk = 32; msk > 0; msk >>= 1) v += __shfl_down(v, msk);
    if (t == 0) out[b] = v + b2l[0];
  }
  // T8: diff + targets (block 0)
  if (b == 0) {
    if (t < 256) dred[t] = diffpart[t];
    __syncthreads();
    for (int off = 128; off > 0; off >>= 1) {
      if (t < off) dred[t] += dred[t+off];
      __syncthreads();
    }
    if (t == 0) out[4] = dred[0] / (float)((float)BB*LL*LL);
    if (t < 4) out[5+t] = targets[t*LL];
  }
}

extern "C" void kernel_launch(void* const* d_in, const int* in_sizes, int n_in,
                              void* d_out, int out_size, void* d_ws, size_t ws_size,
                              hipStream_t stream) {
  const float* inputs  = (const float*)d_in[0];
  const float* coords  = (const float*)d_in[1];
  const float* targets = (const float*)d_in[2];
  const float* cc      = (const float*)d_in[3];
  const float* Wc  = (const float*)d_in[5];
  const float* bc  = (const float*)d_in[6];
  const float* Wcc = (const float*)d_in[7];
  const float* bcc = (const float*)d_in[8];
  const float* Wa  = (const float*)d_in[9];
  const float* ba  = (const float*)d_in[10];
  const float* Wb  = (const float*)d_in[11];
  const float* bb  = (const float*)d_in[12];
  const float* W1l = (const float*)d_in[13];
  const float* b1l = (const float*)d_in[14];
  const float* W1r = (const float*)d_in[15];
  const float* W2l = (const float*)d_in[16];
  const float* b2l = (const float*)d_in[17];
  const float* W2r = (const float*)d_in[18];
  float* out = (float*)d_out;

  float* ws = (float*)d_ws;
  float* Pg = ws;                                  // NROW*DD
  float* Qg = ws + (size_t)NROW*DD;                // NROW*DD
  float* diffpart = ws + (size_t)2*NROW*DD;        // 256
  float* minval   = diffpart + 256;                // NROW*8
  int*   minidx   = (int*)(minval + (size_t)NROW*8);

  k_fused<<<dim3(8, 8, 4), 256, 0, stream>>>(inputs, coords, cc, Wc, bc, Wcc, bcc,
                                             Wa, ba, Wb, bb, diffpart, minval, minidx);
  k_tail2<<<4, 1024, 0, stream>>>(inputs, coords, cc, Wc, bc, Wcc, bcc,
                                  W1l, b1l, W1r, minval, minidx, diffpart, targets,
                                  W2l, b2l, W2r, Pg, Qg, out);
}